// Round 7
// baseline (217.428 us; speedup 1.0000x reference)
//
#include <hip/hip_runtime.h>

// Linformer attention, bf16 MFMA. B=4, L=2048, D=1024, H=16, K=256, DH=64.
//
//  prep:  prepX (one launch, z-switched): x->xb/xTb, proj->projT, W->bf16
//  1. xqb   = xb @ Wq^T             gemm8p (256x128 tile, counted-vmcnt pipe)
//  2. xk2b/xv2b = projT @ xT[b]^T   gemm_p64x128 (64x128 tile, 2x4 wave frags)
//  3. keysb = xk2b @ Wk^T (z=0); vT = (xv2b @ Wv^T)^T in-epilogue (z=1)
//  4. attn_mfma: 8-wave blocks (4 waves/SIMD -- R6 was latency-bound at 2),
//     LDS-staged K/V double-buffer + T14 issue-early/write-late + setprio.
//  5. out   = out2b @ Wo^T + bo     gemm8p
//
// GEMM kernels share the counted-vmcnt schedule: 3 LDS buffers, prefetch
// distance 2 K-tiles, s_waitcnt vmcnt(N) with N = issues/tile (never 0 in
// steady state), one raw s_barrier per tile, setprio around MFMA clusters,
// source-slot pre-swizzle s^((row>>1)&3) on BOTH staging source and ds_read.

typedef __attribute__((ext_vector_type(8))) short short8;
typedef __attribute__((ext_vector_type(4))) short short4_t;
typedef __attribute__((ext_vector_type(4))) float facc;

#define B_    4
#define L_    2048
#define D_    1024
#define H_    16
#define KP    256
#define DH_   64
#define SCALE_ 0.125f
#define PTS   76        // Pt row stride (shorts): 4g*76/2 mod 32 = {0,24,16,8}

__device__ __forceinline__ short f2b(float f) {   // RNE fp32->bf16
  unsigned u = __float_as_uint(f);
  unsigned r = (u + 0x7fffu + ((u >> 16) & 1u)) >> 16;
  return (short)r;
}

// async 16B/lane global->LDS. LDS dest = wave-uniform base + lane*16.
__device__ __forceinline__ void load16_to_lds(const short* gp, short* lp) {
  __builtin_amdgcn_global_load_lds(
      (const __attribute__((address_space(1))) void*)gp,
      (__attribute__((address_space(3))) void*)lp, 16, 0, 0);
}

// ---------------- unified prep kernel, grid (32,64,8) x 256 ----------------
__global__ __launch_bounds__(256) void prepX(
    const float* __restrict__ x,  const float* __restrict__ pk,
    const float* __restrict__ pv, const float* __restrict__ w0,
    const float* __restrict__ w1, const float* __restrict__ w2,
    const float* __restrict__ w3, short* __restrict__ xb,
    short* __restrict__ xTb, short* __restrict__ projT,
    short* __restrict__ Wb)
{
  const int z = blockIdx.z, tid = threadIdx.x;
  if (z >= 6) {            // ---- weight cast: widx = (z-6)*2 + (bid>>10)
    const int bid  = blockIdx.y * 32 + blockIdx.x;
    const int widx = (z - 6) * 2 + (bid >> 10);
    const float* s = (widx == 0) ? w0 : (widx == 1) ? w1 : (widx == 2) ? w2 : w3;
    const int i = ((bid & 1023) * 256 + tid) * 4;
    float4 f = *(const float4*)(s + i);
    short4_t v; v[0] = f2b(f.x); v[1] = f2b(f.y); v[2] = f2b(f.z); v[3] = f2b(f.w);
    *(short4_t*)(Wb + (size_t)widx * 1048576 + i) = v;
    return;
  }

  __shared__ float tl[32][37];
  const int row = tid >> 3, c4 = tid & 7;   // 32 rows x 8 float4 cols

  if (z < 4) {             // ---- x[b]: cast row-major + transpose
    const int b = z, l0 = blockIdx.y * 32, d0 = blockIdx.x * 32;
    const float* s = x + (size_t)b * L_ * D_;
    float4 f = *(const float4*)(s + (size_t)(l0 + row) * D_ + d0 + c4 * 4);
    short4_t v; v[0] = f2b(f.x); v[1] = f2b(f.y); v[2] = f2b(f.z); v[3] = f2b(f.w);
    *(short4_t*)(xb + (size_t)b * L_ * D_ + (size_t)(l0 + row) * D_ + d0 + c4 * 4) = v;
    tl[row][c4 * 4 + 0] = f.x; tl[row][c4 * 4 + 1] = f.y;
    tl[row][c4 * 4 + 2] = f.z; tl[row][c4 * 4 + 3] = f.w;
    __syncthreads();
    short4_t t;
#pragma unroll
    for (int j = 0; j < 4; j++) t[j] = f2b(tl[c4 * 4 + j][row]);
    *(short4_t*)(xTb + (size_t)b * D_ * L_ + (size_t)(d0 + row) * L_ + l0 + c4 * 4) = t;
  } else {                 // ---- projT[sel][kp][l]
    if (blockIdx.x >= 8) return;          // KP=256 -> 8 col-tiles only
    const int sel = z - 4, l0 = blockIdx.y * 32, k0 = blockIdx.x * 32;
    const float* s = sel ? pv : pk;
    float4 f = *(const float4*)(s + (size_t)(l0 + row) * KP + k0 + c4 * 4);
    tl[row][c4 * 4 + 0] = f.x; tl[row][c4 * 4 + 1] = f.y;
    tl[row][c4 * 4 + 2] = f.z; tl[row][c4 * 4 + 3] = f.w;
    __syncthreads();
    short4_t t;
#pragma unroll
    for (int j = 0; j < 4; j++) t[j] = f2b(tl[c4 * 4 + j][row]);
    *(short4_t*)(projT + (size_t)sel * (KP * L_) + (size_t)(k0 + row) * L_ + l0 + c4 * 4) = t;
  }
}

// ---------------- deep-pipelined 256x128 GEMM (counted vmcnt) --------------
__global__ __launch_bounds__(512, 2) void gemm8p(
    const short* __restrict__ Am, const short* __restrict__ Bm,
    const float* __restrict__ bias, float* __restrict__ C32,
    short* __restrict__ Cb, int M, int N, int K)
{
  extern __shared__ __attribute__((aligned(16))) short smem[];
  constexpr int BUF  = 24576;   // shorts per buffer (48KB)
  constexpr int BOFF = 16384;   // B region offset (shorts)

  const int t = threadIdx.x, lane = t & 63, w = t >> 6;
  const int lm = lane & 15, g = lane >> 4;
  const int bm = blockIdx.x * 4 + (blockIdx.y >> 3);
  const int bn = blockIdx.y & 7;
  const int m0 = bm * 256, n0 = bn * 128;
  const int wm = (w & 3) * 64, wn = (w >> 2) * 64;

  const int srow = lane >> 2;     // 0..15 within staging group
  const int sslot = lane & 3;     // physical 16B slot

  facc acc[4][4];
  const facc fz = {0.f, 0.f, 0.f, 0.f};
#pragma unroll
  for (int i = 0; i < 4; i++)
#pragma unroll
    for (int j = 0; j < 4; j++) acc[i][j] = fz;

  auto stageA = [&](int kt, int buf, int rnd) {
    const int task = rnd * 8 + w;
    const int c = task >> 4, grp = task & 15;
    const int row = grp * 16 + srow;
    const int slot = sslot ^ ((row >> 1) & 3);
    load16_to_lds(Am + (size_t)(m0 + row) * K + kt * 64 + c * 32 + slot * 8,
                  smem + buf * BUF + c * 8192 + grp * 512);
  };
  auto stageB = [&](int kt, int buf, int rnd) {
    const int task = rnd * 8 + w;
    const int c = task >> 3, grp = task & 7;
    const int row = grp * 16 + srow;
    const int slot = sslot ^ ((row >> 1) & 3);
    load16_to_lds(Bm + (size_t)(n0 + row) * K + kt * 64 + c * 32 + slot * 8,
                  smem + buf * BUF + BOFF + c * 4096 + grp * 512);
  };

  // prologue: stage tiles 0,1 into buffers 0,1; wait tile0 (12 -> 6 in flight)
#pragma unroll
  for (int r = 0; r < 4; r++) stageA(0, 0, r);
#pragma unroll
  for (int r = 0; r < 2; r++) stageB(0, 0, r);
#pragma unroll
  for (int r = 0; r < 4; r++) stageA(1, 1, r);
#pragma unroll
  for (int r = 0; r < 2; r++) stageB(1, 1, r);
  asm volatile("s_waitcnt vmcnt(6)" ::: "memory");
  __builtin_amdgcn_sched_barrier(0);
  __builtin_amdgcn_s_barrier();

  const int T = K >> 6;
  int p = 0;                         // buffer holding tile kt
  for (int kt = 0; kt < T; kt++) {
    const int q = (p == 0) ? 2 : p - 1;       // buffer for tile kt+2
    const bool pf = (kt + 2 < T);

#pragma unroll
    for (int c = 0; c < 2; c++) {    // two 32-K phases per tile
      short8 af[4], bf[4];
      const int abase = p * BUF + c * 8192;
      const int bbase = p * BUF + BOFF + c * 4096;
#pragma unroll
      for (int mt = 0; mt < 4; mt++) {
        const int row = wm + 16 * mt + lm;
        af[mt] = *(const short8*)(smem + abase + row * 32 + ((g ^ ((row >> 1) & 3)) * 8));
      }
#pragma unroll
      for (int nt = 0; nt < 4; nt++) {
        const int row = wn + 16 * nt + lm;
        bf[nt] = *(const short8*)(smem + bbase + row * 32 + ((g ^ ((row >> 1) & 3)) * 8));
      }
      if (pf) {                      // 3 staging issues per phase
        if (c == 0) { stageA(kt + 2, q, 0); stageA(kt + 2, q, 1); stageB(kt + 2, q, 0); }
        else        { stageA(kt + 2, q, 2); stageA(kt + 2, q, 3); stageB(kt + 2, q, 1); }
      }
      __builtin_amdgcn_s_barrier();
      __builtin_amdgcn_s_setprio(1);
#pragma unroll
      for (int mt = 0; mt < 4; mt++)
#pragma unroll
        for (int nt = 0; nt < 4; nt++)
          acc[mt][nt] = __builtin_amdgcn_mfma_f32_16x16x32_bf16(af[mt], bf[nt], acc[mt][nt], 0, 0, 0);
      __builtin_amdgcn_s_setprio(0);
      if (c == 0) __builtin_amdgcn_s_barrier();
    }

    if (pf) {
      asm volatile("s_waitcnt vmcnt(6)" ::: "memory");
      __builtin_amdgcn_sched_barrier(0);
    } else if (kt + 1 < T) {
      asm volatile("s_waitcnt vmcnt(0)" ::: "memory");
      __builtin_amdgcn_sched_barrier(0);
    }
    __builtin_amdgcn_s_barrier();
    p = (p == 2) ? 0 : p + 1;
  }

  // epilogue
#pragma unroll
  for (int mt = 0; mt < 4; mt++)
#pragma unroll
    for (int r = 0; r < 4; r++) {
      const int row = m0 + wm + 16 * mt + 4 * g + r;
#pragma unroll
      for (int nt = 0; nt < 4; nt++) {
        const int col = n0 + wn + 16 * nt + lm;
        float v = acc[mt][nt][r];
        if (bias) v += bias[col];
        if (C32) C32[(size_t)row * N + col] = v;
        if (Cb)  Cb[(size_t)row * N + col] = f2b(v);
      }
    }
}

// ---------------- deep-pipelined 64x128 GEMM, 4 waves, 2x4 wave frags ------
__global__ __launch_bounds__(256) void gemm_p64x128(
    const short* __restrict__ Am, const short* __restrict__ Bm,
    const float* __restrict__ bias, float* __restrict__ C32,
    short* __restrict__ Cb, short* __restrict__ CbT, int M, int N, int K,
    long aHi, long aLo, long bHi, long bLo, long cHi, long cLo, int zDiv)
{
  __shared__ __attribute__((aligned(16))) short smem[3 * 12288];   // 72KB
  const int t = threadIdx.x, lane = t & 63, w = t >> 6;
  const int lm = lane & 15, g = lane >> 4;
  const int z = blockIdx.z, zhi = z / zDiv, zlo = z % zDiv;
  const int m0 = blockIdx.y * 64, n0 = blockIdx.x * 128;
  const int wm = (w & 1) * 32, wn = (w >> 1) * 64;

  const short* Ab = Am + zhi * aHi + zlo * aLo;
  const short* Bp = Bm + zhi * bHi + zlo * bLo;

  const int srow = lane >> 2;                     // 0..15
  const int sslot = lane & 3;

  facc acc[2][4];
  const facc fz = {0.f, 0.f, 0.f, 0.f};
#pragma unroll
  for (int i = 0; i < 2; i++)
#pragma unroll
    for (int j = 0; j < 4; j++) acc[i][j] = fz;

  // stage chunk c (32-K) of tile kt into buf: A 1 issue + B 2 issues per wave
  auto stage_h = [&](int kt, int buf, int c) {
    const int arow = w * 16 + srow;                       // A rows 0..63
    const int aslot = sslot ^ ((arow >> 1) & 3);
    load16_to_lds(Ab + (size_t)(m0 + arow) * K + kt * 64 + c * 32 + aslot * 8,
                  smem + buf * 12288 + c * 2048 + w * 512);
#pragma unroll
    for (int jj = 0; jj < 2; jj++) {
      const int j = w + jj * 4;                           // B row-groups 0..7
      const int brow = j * 16 + srow;
      const int bslot = sslot ^ ((brow >> 1) & 3);
      load16_to_lds(Bp + (size_t)(n0 + brow) * K + kt * 64 + c * 32 + bslot * 8,
                    smem + buf * 12288 + 4096 + c * 4096 + j * 512);
    }
  };

  // prologue: stage tiles 0,1 (12 issues); wait tile0 (6 remain in flight)
  stage_h(0, 0, 0); stage_h(0, 0, 1);
  stage_h(1, 1, 0); stage_h(1, 1, 1);
  asm volatile("s_waitcnt vmcnt(6)" ::: "memory");
  __builtin_amdgcn_sched_barrier(0);
  __builtin_amdgcn_s_barrier();

  const int T = K >> 6;
  int p = 0;                          // buffer holding tile kt
  for (int kt = 0; kt < T; kt++) {
    const int q = (p == 0) ? 2 : p - 1;       // buffer for tile kt+2
    const bool pf = (kt + 2 < T);

#pragma unroll
    for (int c = 0; c < 2; c++) {     // two 32-K phases per tile
      short8 af[2], bf[4];
      const int abase = p * 12288 + c * 2048;
      const int bbase = p * 12288 + 4096 + c * 4096;
#pragma unroll
      for (int mt = 0; mt < 2; mt++) {
        const int row = wm + 16 * mt + lm;
        af[mt] = *(const short8*)(smem + abase + row * 32 + ((g ^ ((row >> 1) & 3)) * 8));
      }
#pragma unroll
      for (int nt = 0; nt < 4; nt++) {
        const int row = wn + 16 * nt + lm;
        bf[nt] = *(const short8*)(smem + bbase + row * 32 + ((g ^ ((row >> 1) & 3)) * 8));
      }
      if (pf) stage_h(kt + 2, q, c);
      __builtin_amdgcn_s_setprio(1);
#pragma unroll
      for (int mt = 0; mt < 2; mt++)
#pragma unroll
        for (int nt = 0; nt < 4; nt++)
          acc[mt][nt] = __builtin_amdgcn_mfma_f32_16x16x32_bf16(af[mt], bf[nt], acc[mt][nt], 0, 0, 0);
      __builtin_amdgcn_s_setprio(0);
    }

    // tile end: confirm tile kt+1 landed (its 6 issues are oldest in flight)
    if (pf) {
      asm volatile("s_waitcnt vmcnt(6)" ::: "memory");
      __builtin_amdgcn_sched_barrier(0);
    } else if (kt + 1 < T) {
      asm volatile("s_waitcnt vmcnt(0)" ::: "memory");
      __builtin_amdgcn_sched_barrier(0);
    }
    __builtin_amdgcn_s_barrier();
    p = (p == 2) ? 0 : p + 1;
  }

  if (CbT && zhi == 1) {
    // vals slice -> vT [b][h=col>>6][dh=col&63][kp=row&255], b = row>>8
#pragma unroll
    for (int mt = 0; mt < 2; mt++) {
      const int rb = m0 + wm + 16 * mt + 4 * g;          // multiple of 4
      const size_t bb = (size_t)(rb >> 8) * (16 * 64 * 256);
      const int kp = rb & 255;
#pragma unroll
      for (int nt = 0; nt < 4; nt++) {
        const int col = n0 + wn + 16 * nt + lm;
        short4_t o4;
#pragma unroll
        for (int r = 0; r < 4; r++) o4[r] = f2b(acc[mt][nt][r]);
        *(short4_t*)(CbT + bb + (size_t)col * KP + kp) = o4;
      }
    }
    return;
  }

  const long cz = zhi * cHi + zlo * cLo;
#pragma unroll
  for (int mt = 0; mt < 2; mt++)
#pragma unroll
    for (int r = 0; r < 4; r++) {
      const int row = m0 + wm + 16 * mt + 4 * g + r;
#pragma unroll
      for (int nt = 0; nt < 4; nt++) {
        const int col = n0 + wn + 16 * nt + lm;
        float v = acc[mt][nt][r];
        if (bias) v += bias[col];
        if (C32) C32[cz + (size_t)row * N + col] = v;
        if (Cb)  Cb[cz + (size_t)row * N + col] = f2b(v);
      }
    }
}

// ---------------- fused MFMA attention: 8 waves, T14, dbuf, setprio --------
// 512 threads, grid (8,16,4) = 512 blocks = 2/CU. LDS 74KB -> 2 blocks/CU
// -> 16 waves/CU = 4 waves/SIMD (2x the 4-wave version: R5/R6 showed the
// chunk pipeline is latency-bound, both MFMA and VALU pipes mostly idle).
// Each wave owns 32 l-rows; K/V staged once per 256-row block (halved
// global K/V traffic); per-wave softmax/PV identical to the 4-wave version.
__global__ __launch_bounds__(512) void attn_mfma(
    const short* __restrict__ xqb, const short* __restrict__ keysb,
    const short* __restrict__ vTb, short* __restrict__ out2b)
{
  __shared__ __attribute__((aligned(16))) short Kt[2][64 * 72];   // kp x d
  __shared__ __attribute__((aligned(16))) short Vt[2][64 * 72];   // d x kp
  __shared__ __attribute__((aligned(16))) short Pt[8][32 * PTS];  // per-wave l x kp

  const int t = threadIdx.x, lane = t & 63, w = t >> 6;   // w = 0..7
  const int lm = lane & 15, g = lane >> 4;
  const int b = blockIdx.z, h = blockIdx.y;
  const int l0w = blockIdx.x * 256 + w * 32;

  // q frags (plain-reshape q): row = h*128 + l/16, col = (l%16)*64 + d
  short8 aq[2][2];
#pragma unroll
  for (int mt = 0; mt < 2; mt++) {
    const int l = l0w + 16 * mt + lm;
    const short* qrow = xqb + ((size_t)b * L_ + h * 128 + (l >> 4)) * D_ + (l & 15) * DH_;
#pragma unroll
    for (int ks = 0; ks < 2; ks++)
      aq[mt][ks] = *(const short8*)(qrow + ks * 32 + g * 8);
  }

  facc accO[2][4];
  const facc fz = {0.f, 0.f, 0.f, 0.f};
#pragma unroll
  for (int mt = 0; mt < 2; mt++)
#pragma unroll
    for (int dt = 0; dt < 4; dt++) accO[mt][dt] = fz;
  float lrow[2][4];
#pragma unroll
  for (int mt = 0; mt < 2; mt++)
#pragma unroll
    for (int r = 0; r < 4; r++) lrow[mt][r] = 0.f;

  const short* Kb = keysb + (size_t)b * KP * D_ + h * DH_;
  const short* Vb = vTb + ((size_t)b * H_ + h) * DH_ * KP;

  const int srow = t >> 3, sch = (t & 7) * 8;   // 512 thr: 64 rows x 8 chunks

  // stage chunk 0 into buffer 0 (one K-row + one V-row per thread)
  *(short8*)(&Kt[0][srow * 72 + sch]) = *(const short8*)(Kb + (size_t)srow * D_ + sch);
  *(short8*)(&Vt[0][srow * 72 + sch]) = *(const short8*)(Vb + (size_t)srow * KP + sch);
  __syncthreads();

  for (int c = 0; c < 4; c++) {        // kp chunks of 64
    const int bi = c & 1;

    // T14 issue-early: next chunk's K/V global->reg (latency hides under QK)
    short8 kr, vr;
    if (c < 3) {
      kr = *(const short8*)(Kb + (size_t)((c + 1) * 64 + srow) * D_ + sch);
      vr = *(const short8*)(Vb + (size_t)srow * KP + (c + 1) * 64 + sch);
    }

    // QK^T
    facc S[2][4];
#pragma unroll
    for (int mt = 0; mt < 2; mt++)
#pragma unroll
      for (int nt = 0; nt < 4; nt++) S[mt][nt] = fz;
#pragma unroll
    for (int ks = 0; ks < 2; ks++) {
      short8 bk[4];
#pragma unroll
      for (int nt = 0; nt < 4; nt++)
        bk[nt] = *(const short8*)(&Kt[bi][(16 * nt + lm) * 72 + ks * 32 + g * 8]);
      __builtin_amdgcn_s_setprio(1);
#pragma unroll
      for (int mt = 0; mt < 2; mt++)
#pragma unroll
        for (int nt = 0; nt < 4; nt++)
          S[mt][nt] = __builtin_amdgcn_mfma_f32_16x16x32_bf16(aq[mt][ks], bk[nt], S[mt][nt], 0, 0, 0);
      __builtin_amdgcn_s_setprio(0);
    }

    // T14 write-late: commit staged regs to the other buffer
    if (c < 3) {
      *(short8*)(&Kt[bi ^ 1][srow * 72 + sch]) = kr;
      *(short8*)(&Vt[bi ^ 1][srow * 72 + sch]) = vr;
    }

    // exp (no max) + P -> LDS (bf16)
#pragma unroll
    for (int mt = 0; mt < 2; mt++)
#pragma unroll
      for (int r = 0; r < 4; r++) {
        float ps = 0.f;
        const int prow = (16 * mt + 4 * g + r) * PTS;
#pragma unroll
        for (int nt = 0; nt < 4; nt++) {
          const float p = __expf(S[mt][nt][r] * SCALE_);
          ps += p;
          Pt[w][prow + 16 * nt + lm] = f2b(p);
        }
        lrow[mt][r] += ps;
      }
    // same-wave LDS RAW: in-order DS pipe, no barrier needed

    // PV
#pragma unroll
    for (int ks = 0; ks < 2; ks++) {
      short8 ap[2], bv[4];
#pragma unroll
      for (int mt = 0; mt < 2; mt++)
        ap[mt] = *(const short8*)(&Pt[w][(16 * mt + lm) * PTS + ks * 32 + g * 8]);
#pragma unroll
      for (int dt = 0; dt < 4; dt++)
        bv[dt] = *(const short8*)(&Vt[bi][(16 * dt + lm) * 72 + ks * 32 + g * 8]);
      __builtin_amdgcn_s_setprio(1);
#pragma unroll
      for (int mt = 0; mt < 2; mt++)
#pragma unroll
        for (int dt = 0; dt < 4; dt++)
          accO[mt][dt] = __builtin_amdgcn_mfma_f32_16x16x32_bf16(ap[mt], bv[dt], accO[mt][dt], 0, 0, 0);
      __builtin_amdgcn_s_setprio(0);
    }
    __syncthreads();   // all waves done with buffer bi before it's restaged
  }

  // epilogue: reduce lsum across the 16 lanes of each row, scale, store bf16
#pragma unroll
  for (int mt = 0; mt < 2; mt++)
#pragma unroll
    for (int r = 0; r < 4; r++) {
      float ls = lrow[mt][r];
      ls += __shfl_xor(ls, 1);
      ls += __shfl_xor(ls, 2);
      ls += __shfl_xor(ls, 4);
      ls += __shfl_xor(ls, 8);
      const float inv = 1.0f / ls;
      const int l = l0w + 16 * mt + 4 * g + r;
#pragma unroll
      for (int dt = 0; dt < 4; dt++)
        out2b[((size_t)b * L_ + l) * D_ + h * DH_ + 16 * dt + lm] = f2b(accO[mt][dt][r] * inv);
    }
}

extern "C" void kernel_launch(void* const* d_in, const int* in_sizes, int n_in,
                              void* d_out, int out_size, void* d_ws, size_t ws_size,
                              hipStream_t stream)
{
  const float* x      = (const float*)d_in[0];
  const float* Wq     = (const float*)d_in[1];
  const float* Wk     = (const float*)d_in[2];
  const float* Wv     = (const float*)d_in[3];
  const float* proj_k = (const float*)d_in[4];
  const float* proj_v = (const float*)d_in[5];
  const float* Wo     = (const float*)d_in[6];
  const float* bo     = (const float*)d_in[7];
  float* out = (float*)d_out;

  short* ws     = (short*)d_ws;
  short* xqb    = ws;                    // 8388608
  short* xTb    = xqb    + 8388608;      // 8388608  [B][D][L]
  short* xb     = xTb    + 8388608;      // 8388608
  short* out2b  = xb;                    //          alias (xb dead after gemm1)
  short* Wqb    = xb     + 8388608;      // 1048576 (Wq,Wk,Wv,Wo contiguous)
  short* Wkb    = Wqb    + 1048576;
  short* Wvb    = Wkb    + 1048576;
  short* Wob    = Wvb    + 1048576;
  short* projTk = Wob    + 1048576;      // 524288 (projTk,projTv contiguous)
  short* projTv = projTk + 524288;
  short* xk2b   = projTv + 524288;       // 1048576 (adjacent xv2b)
  short* xv2b   = xk2b   + 1048576;
  short* keysb  = xv2b   + 1048576;
  short* valsb  = keysb  + 1048576;
  short* vT     = valsb  + 1048576;      // 1048576 [B][H][64][256]
  (void)Wkb; (void)Wvb; (void)projTv; (void)xv2b; (void)valsb;

  static bool attr_set = false;
  if (!attr_set) {
    (void)hipFuncSetAttribute(reinterpret_cast<const void*>(gemm8p),
                              hipFuncAttributeMaxDynamicSharedMemorySize, 147456);
    attr_set = true;
  }

  prepX<<<dim3(32, 64, 8), 256, 0, stream>>>(
      x, proj_k, proj_v, Wq, Wk, Wv, Wo, xb, xTb, projTk, Wqb);

  // 1. xqb = xb @ Wq^T   (grid (8 xcd-bands, 32), 512 thr, 144KB dyn LDS)
  gemm8p<<<dim3(8, 32, 1), 512, 147456, stream>>>(
      xb, Wqb, nullptr, nullptr, xqb, 8192, 1024, 1024);

  // 2. xk2b/xv2b = projT @ xT[b]^T  (z = sel*4 + b), 64x128 pipelined
  gemm_p64x128<<<dim3(8, 4, 8), 256, 0, stream>>>(
      projTk, xTb, nullptr, nullptr, xk2b, nullptr, 256, 1024, 2048,
      524288, 0, 0, (long)D_ * L_, 1048576, 262144, 4);

  // 3. keysb = xk2b @ Wk^T (z=0); vT = transpose(xv2b @ Wv^T) (z=1)
  gemm_p64x128<<<dim3(8, 16, 2), 256, 0, stream>>>(
      xk2b, Wkb, nullptr, nullptr, keysb, vT, 1024, 1024, 1024,
      1048576, 0, 1048576, 0, 0, 0, 1);

  // 4. attention (8-wave, LDS-staged, T14, dbuf, setprio)
  attn_mfma<<<dim3(8, 16, 4), 512, 0, stream>>>(xqb, keysb, vT, out2b);

  // 5. out = out2b @ Wo^T + bo (fp32 out)
  gemm8p<<<dim3(8, 32, 1), 512, 147456, stream>>>(
      out2b, Wob, bo, out, nullptr, 8192, 1024, 1024);
}

// Round 9
// 215.997 us; speedup vs baseline: 1.0066x; 1.0066x over previous
//
#include <hip/hip_runtime.h>

// Linformer attention, bf16 MFMA. B=4, L=2048, D=1024, H=16, K=256, DH=64.
//
//  prep:  prepX (one launch, z-switched): x->xb/xTb, proj->projT, W->bf16
//  1. xqb   = xb @ Wq^T             gemm8p (256x128 tile, counted-vmcnt pipe)
//  2. xk2b/xv2b = projT @ xT[b]^T   gemm_p64 (64x64 tile, counted-vmcnt pipe)
//  3. keysb = xk2b @ Wk^T (z=0); vT = (xv2b @ Wv^T)^T in-epilogue (z=1)
//  4. attn_mfma: QK^T -> exp (no max; |s|<~5) -> PV -> out2b
//     T14 staging: global->reg issued before QK, LDS write after QK.
//  5. out   = out2b @ Wo^T + bo     gemm8p
//
// Both GEMM kernels share the counted-vmcnt schedule: 3 LDS buffers,
// prefetch distance 2 K-tiles, s_waitcnt vmcnt(N) with N = issues/tile
// (never 0 in steady state), one raw s_barrier per tile, setprio around
// MFMA clusters, source-slot pre-swizzle s^((row>>1)&3) applied on BOTH
// the staging source and the ds_read address (bank-optimal 8 words/bank).

typedef __attribute__((ext_vector_type(8))) short short8;
typedef __attribute__((ext_vector_type(4))) short short4_t;
typedef __attribute__((ext_vector_type(4))) float facc;

#define B_    4
#define L_    2048
#define D_    1024
#define H_    16
#define KP    256
#define DH_   64
#define SCALE_ 0.125f
#define PTS   76        // Pt row stride (shorts): 4g*76/2 mod 32 = {0,24,16,8}

__device__ __forceinline__ short f2b(float f) {   // RNE fp32->bf16
  unsigned u = __float_as_uint(f);
  unsigned r = (u + 0x7fffu + ((u >> 16) & 1u)) >> 16;
  return (short)r;
}

// async 16B/lane global->LDS. LDS dest = wave-uniform base + lane*16.
__device__ __forceinline__ void load16_to_lds(const short* gp, short* lp) {
  __builtin_amdgcn_global_load_lds(
      (const __attribute__((address_space(1))) void*)gp,
      (__attribute__((address_space(3))) void*)lp, 16, 0, 0);
}

// ---------------- unified prep kernel, grid (32,64,8) x 256 ----------------
__global__ __launch_bounds__(256) void prepX(
    const float* __restrict__ x,  const float* __restrict__ pk,
    const float* __restrict__ pv, const float* __restrict__ w0,
    const float* __restrict__ w1, const float* __restrict__ w2,
    const float* __restrict__ w3, short* __restrict__ xb,
    short* __restrict__ xTb, short* __restrict__ projT,
    short* __restrict__ Wb)
{
  const int z = blockIdx.z, tid = threadIdx.x;
  if (z >= 6) {            // ---- weight cast: widx = (z-6)*2 + (bid>>10)
    const int bid  = blockIdx.y * 32 + blockIdx.x;
    const int widx = (z - 6) * 2 + (bid >> 10);
    const float* s = (widx == 0) ? w0 : (widx == 1) ? w1 : (widx == 2) ? w2 : w3;
    const int i = ((bid & 1023) * 256 + tid) * 4;
    float4 f = *(const float4*)(s + i);
    short4_t v; v[0] = f2b(f.x); v[1] = f2b(f.y); v[2] = f2b(f.z); v[3] = f2b(f.w);
    *(short4_t*)(Wb + (size_t)widx * 1048576 + i) = v;
    return;
  }

  __shared__ float tl[32][37];
  const int row = tid >> 3, c4 = tid & 7;   // 32 rows x 8 float4 cols

  if (z < 4) {             // ---- x[b]: cast row-major + transpose
    const int b = z, l0 = blockIdx.y * 32, d0 = blockIdx.x * 32;
    const float* s = x + (size_t)b * L_ * D_;
    float4 f = *(const float4*)(s + (size_t)(l0 + row) * D_ + d0 + c4 * 4);
    short4_t v; v[0] = f2b(f.x); v[1] = f2b(f.y); v[2] = f2b(f.z); v[3] = f2b(f.w);
    *(short4_t*)(xb + (size_t)b * L_ * D_ + (size_t)(l0 + row) * D_ + d0 + c4 * 4) = v;
    tl[row][c4 * 4 + 0] = f.x; tl[row][c4 * 4 + 1] = f.y;
    tl[row][c4 * 4 + 2] = f.z; tl[row][c4 * 4 + 3] = f.w;
    __syncthreads();
    short4_t t;
#pragma unroll
    for (int j = 0; j < 4; j++) t[j] = f2b(tl[c4 * 4 + j][row]);
    *(short4_t*)(xTb + (size_t)b * D_ * L_ + (size_t)(d0 + row) * L_ + l0 + c4 * 4) = t;
  } else {                 // ---- projT[sel][kp][l]
    if (blockIdx.x >= 8) return;          // KP=256 -> 8 col-tiles only
    const int sel = z - 4, l0 = blockIdx.y * 32, k0 = blockIdx.x * 32;
    const float* s = sel ? pv : pk;
    float4 f = *(const float4*)(s + (size_t)(l0 + row) * KP + k0 + c4 * 4);
    tl[row][c4 * 4 + 0] = f.x; tl[row][c4 * 4 + 1] = f.y;
    tl[row][c4 * 4 + 2] = f.z; tl[row][c4 * 4 + 3] = f.w;
    __syncthreads();
    short4_t t;
#pragma unroll
    for (int j = 0; j < 4; j++) t[j] = f2b(tl[c4 * 4 + j][row]);
    *(short4_t*)(projT + (size_t)sel * (KP * L_) + (size_t)(k0 + row) * L_ + l0 + c4 * 4) = t;
  }
}

// ---------------- deep-pipelined 256x128 GEMM (counted vmcnt) --------------
__global__ __launch_bounds__(512, 2) void gemm8p(
    const short* __restrict__ Am, const short* __restrict__ Bm,
    const float* __restrict__ bias, float* __restrict__ C32,
    short* __restrict__ Cb, int M, int N, int K)
{
  extern __shared__ __attribute__((aligned(16))) short smem[];
  constexpr int BUF  = 24576;   // shorts per buffer (48KB)
  constexpr int BOFF = 16384;   // B region offset (shorts)

  const int t = threadIdx.x, lane = t & 63, w = t >> 6;
  const int lm = lane & 15, g = lane >> 4;
  const int bm = blockIdx.x * 4 + (blockIdx.y >> 3);
  const int bn = blockIdx.y & 7;
  const int m0 = bm * 256, n0 = bn * 128;
  const int wm = (w & 3) * 64, wn = (w >> 2) * 64;

  const int srow = lane >> 2;     // 0..15 within staging group
  const int sslot = lane & 3;     // physical 16B slot

  facc acc[4][4];
  const facc fz = {0.f, 0.f, 0.f, 0.f};
#pragma unroll
  for (int i = 0; i < 4; i++)
#pragma unroll
    for (int j = 0; j < 4; j++) acc[i][j] = fz;

  auto stageA = [&](int kt, int buf, int rnd) {
    const int task = rnd * 8 + w;
    const int c = task >> 4, grp = task & 15;
    const int row = grp * 16 + srow;
    const int slot = sslot ^ ((row >> 1) & 3);
    load16_to_lds(Am + (size_t)(m0 + row) * K + kt * 64 + c * 32 + slot * 8,
                  smem + buf * BUF + c * 8192 + grp * 512);
  };
  auto stageB = [&](int kt, int buf, int rnd) {
    const int task = rnd * 8 + w;
    const int c = task >> 3, grp = task & 7;
    const int row = grp * 16 + srow;
    const int slot = sslot ^ ((row >> 1) & 3);
    load16_to_lds(Bm + (size_t)(n0 + row) * K + kt * 64 + c * 32 + slot * 8,
                  smem + buf * BUF + BOFF + c * 4096 + grp * 512);
  };

  // prologue: stage tiles 0,1 into buffers 0,1; wait tile0 (12 -> 6 in flight)
#pragma unroll
  for (int r = 0; r < 4; r++) stageA(0, 0, r);
#pragma unroll
  for (int r = 0; r < 2; r++) stageB(0, 0, r);
#pragma unroll
  for (int r = 0; r < 4; r++) stageA(1, 1, r);
#pragma unroll
  for (int r = 0; r < 2; r++) stageB(1, 1, r);
  asm volatile("s_waitcnt vmcnt(6)" ::: "memory");
  __builtin_amdgcn_sched_barrier(0);
  __builtin_amdgcn_s_barrier();

  const int T = K >> 6;
  int p = 0;                         // buffer holding tile kt
  for (int kt = 0; kt < T; kt++) {
    const int q = (p == 0) ? 2 : p - 1;       // buffer for tile kt+2
    const bool pf = (kt + 2 < T);

#pragma unroll
    for (int c = 0; c < 2; c++) {    // two 32-K phases per tile
      short8 af[4], bf[4];
      const int abase = p * BUF + c * 8192;
      const int bbase = p * BUF + BOFF + c * 4096;
#pragma unroll
      for (int mt = 0; mt < 4; mt++) {
        const int row = wm + 16 * mt + lm;
        af[mt] = *(const short8*)(smem + abase + row * 32 + ((g ^ ((row >> 1) & 3)) * 8));
      }
#pragma unroll
      for (int nt = 0; nt < 4; nt++) {
        const int row = wn + 16 * nt + lm;
        bf[nt] = *(const short8*)(smem + bbase + row * 32 + ((g ^ ((row >> 1) & 3)) * 8));
      }
      if (pf) {                      // 3 staging issues per phase
        if (c == 0) { stageA(kt + 2, q, 0); stageA(kt + 2, q, 1); stageB(kt + 2, q, 0); }
        else        { stageA(kt + 2, q, 2); stageA(kt + 2, q, 3); stageB(kt + 2, q, 1); }
      }
      __builtin_amdgcn_s_barrier();
      __builtin_amdgcn_s_setprio(1);
#pragma unroll
      for (int mt = 0; mt < 4; mt++)
#pragma unroll
        for (int nt = 0; nt < 4; nt++)
          acc[mt][nt] = __builtin_amdgcn_mfma_f32_16x16x32_bf16(af[mt], bf[nt], acc[mt][nt], 0, 0, 0);
      __builtin_amdgcn_s_setprio(0);
      if (c == 0) __builtin_amdgcn_s_barrier();
    }

    if (pf) {
      asm volatile("s_waitcnt vmcnt(6)" ::: "memory");
      __builtin_amdgcn_sched_barrier(0);
    } else if (kt + 1 < T) {
      asm volatile("s_waitcnt vmcnt(0)" ::: "memory");
      __builtin_amdgcn_sched_barrier(0);
    }
    __builtin_amdgcn_s_barrier();
    p = (p == 2) ? 0 : p + 1;
  }

  // epilogue
#pragma unroll
  for (int mt = 0; mt < 4; mt++)
#pragma unroll
    for (int r = 0; r < 4; r++) {
      const int row = m0 + wm + 16 * mt + 4 * g + r;
#pragma unroll
      for (int nt = 0; nt < 4; nt++) {
        const int col = n0 + wn + 16 * nt + lm;
        float v = acc[mt][nt][r];
        if (bias) v += bias[col];
        if (C32) C32[(size_t)row * N + col] = v;
        if (Cb)  Cb[(size_t)row * N + col] = f2b(v);
      }
    }
}

// ---------------- deep-pipelined 64x64 GEMM (counted vmcnt), 4 waves -------
// Same schedule as gemm8p at small tile: 3 buffers x 16KB, prefetch dist 2,
// 4 global_load_lds per tile per wave, vmcnt(4) per tile (never 0 until
// tail), 1 s_barrier per tile. Requires K%64==0, K>=128. Bit-identical
// K-accumulation order to the old NC-chunked kernel.
__global__ __launch_bounds__(256) void gemm_p64(
    const short* __restrict__ Am, const short* __restrict__ Bm,
    const float* __restrict__ bias, float* __restrict__ C32,
    short* __restrict__ Cb, short* __restrict__ CbT, int M, int N, int K,
    long aHi, long aLo, long bHi, long bLo, long cHi, long cLo, int zDiv)
{
  __shared__ __attribute__((aligned(16))) short smem[3 * 8192];   // 48KB
  const int t = threadIdx.x, lane = t & 63, w = t >> 6;
  const int lm = lane & 15, g = lane >> 4;
  const int z = blockIdx.z, zhi = z / zDiv, zlo = z % zDiv;
  const int bm = blockIdx.y, bn = blockIdx.x;
  const int m0 = bm * 64, n0 = bn * 64;
  const int wm = (w & 1) * 32, wn = (w >> 1) * 32;

  const short* Ab = Am + zhi * aHi + zlo * aLo;
  const short* Bp = Bm + zhi * bHi + zlo * bLo;

  const int srow = w * 16 + (lane >> 2);          // row this lane stages
  const int pslot = (lane & 3) ^ ((srow >> 1) & 3);  // pre-swizzled src slot

  facc acc[2][2];
  const facc fz = {0.f, 0.f, 0.f, 0.f};
#pragma unroll
  for (int i = 0; i < 2; i++)
#pragma unroll
    for (int j = 0; j < 2; j++) acc[i][j] = fz;

  // stage chunk c (32-K) of tile kt into buf: one A + one B issue per wave
  auto stage_h = [&](int kt, int buf, int c) {
    load16_to_lds(Ab + (size_t)(m0 + srow) * K + kt * 64 + c * 32 + pslot * 8,
                  smem + buf * 8192 + c * 2048 + w * 512);
    load16_to_lds(Bp + (size_t)(n0 + srow) * K + kt * 64 + c * 32 + pslot * 8,
                  smem + buf * 8192 + 4096 + c * 2048 + w * 512);
  };

  // prologue: stage tiles 0,1 (8 issues); wait tile0 (4 remain in flight)
  stage_h(0, 0, 0); stage_h(0, 0, 1);
  stage_h(1, 1, 0); stage_h(1, 1, 1);
  asm volatile("s_waitcnt vmcnt(4)" ::: "memory");
  __builtin_amdgcn_sched_barrier(0);
  __builtin_amdgcn_s_barrier();

  const int T = K >> 6;
  int p = 0;                          // buffer holding tile kt
  for (int kt = 0; kt < T; kt++) {
    const int q = (p == 0) ? 2 : p - 1;       // buffer for tile kt+2
    const bool pf = (kt + 2 < T);

#pragma unroll
    for (int c = 0; c < 2; c++) {     // two 32-K phases per tile
      short8 af[2], bf[2];
      const int abase = p * 8192 + c * 2048;
      const int bbase = p * 8192 + 4096 + c * 2048;
#pragma unroll
      for (int mt = 0; mt < 2; mt++) {
        const int row = wm + 16 * mt + lm;
        af[mt] = *(const short8*)(smem + abase + row * 32 + ((g ^ ((row >> 1) & 3)) * 8));
      }
#pragma unroll
      for (int nt = 0; nt < 2; nt++) {
        const int row = wn + 16 * nt + lm;
        bf[nt] = *(const short8*)(smem + bbase + row * 32 + ((g ^ ((row >> 1) & 3)) * 8));
      }
      if (pf) stage_h(kt + 2, q, c);
      __builtin_amdgcn_s_setprio(1);
#pragma unroll
      for (int mt = 0; mt < 2; mt++)
#pragma unroll
        for (int nt = 0; nt < 2; nt++)
          acc[mt][nt] = __builtin_amdgcn_mfma_f32_16x16x32_bf16(af[mt], bf[nt], acc[mt][nt], 0, 0, 0);
      __builtin_amdgcn_s_setprio(0);
    }

    // tile end: confirm tile kt+1 landed (its 4 issues are oldest in flight)
    if (pf) {
      asm volatile("s_waitcnt vmcnt(4)" ::: "memory");
      __builtin_amdgcn_sched_barrier(0);
    } else if (kt + 1 < T) {
      asm volatile("s_waitcnt vmcnt(0)" ::: "memory");
      __builtin_amdgcn_sched_barrier(0);
    }
    __builtin_amdgcn_s_barrier();
    p = (p == 2) ? 0 : p + 1;
  }

  if (CbT && zhi == 1) {
    // vals slice -> vT [b][h=col>>6][dh=col&63][kp=row&255], b = row>>8
#pragma unroll
    for (int mt = 0; mt < 2; mt++) {
      const int rb = m0 + wm + 16 * mt + 4 * g;          // multiple of 4
      const size_t bb = (size_t)(rb >> 8) * (16 * 64 * 256);
      const int kp = rb & 255;
#pragma unroll
      for (int nt = 0; nt < 2; nt++) {
        const int col = n0 + wn + 16 * nt + lm;
        short4_t o4;
#pragma unroll
        for (int r = 0; r < 4; r++) o4[r] = f2b(acc[mt][nt][r]);
        *(short4_t*)(CbT + bb + (size_t)col * KP + kp) = o4;
      }
    }
    return;
  }

  const long cz = zhi * cHi + zlo * cLo;
#pragma unroll
  for (int mt = 0; mt < 2; mt++)
#pragma unroll
    for (int r = 0; r < 4; r++) {
      const int row = m0 + wm + 16 * mt + 4 * g + r;
#pragma unroll
      for (int nt = 0; nt < 2; nt++) {
        const int col = n0 + wn + 16 * nt + lm;
        float v = acc[mt][nt][r];
        if (bias) v += bias[col];
        if (C32) C32[cz + (size_t)row * N + col] = v;
        if (Cb)  Cb[cz + (size_t)row * N + col] = f2b(v);
      }
    }
}

// ---------------- fused MFMA attention (T14 staging split) ----------------
__global__ __launch_bounds__(256) void attn_mfma(
    const short* __restrict__ xqb, const short* __restrict__ keysb,
    const short* __restrict__ vTb, short* __restrict__ out2b)
{
  __shared__ __attribute__((aligned(16))) short Kt[2][64 * 72];   // kp x d
  __shared__ __attribute__((aligned(16))) short Vt[2][64 * 72];   // d x kp
  __shared__ __attribute__((aligned(16))) short Pt[4][32 * PTS];  // per-wave l x kp

  const int t = threadIdx.x, lane = t & 63, w = t >> 6;
  const int lm = lane & 15, g = lane >> 4;
  const int b = blockIdx.z, h = blockIdx.y;
  const int l0w = blockIdx.x * 128 + w * 32;

  short8 aq[2][2];
#pragma unroll
  for (int mt = 0; mt < 2; mt++) {
    const int l = l0w + 16 * mt + lm;
    const short* qrow = xqb + ((size_t)b * L_ + h * 128 + (l >> 4)) * D_ + (l & 15) * DH_;
#pragma unroll
    for (int ks = 0; ks < 2; ks++)
      aq[mt][ks] = *(const short8*)(qrow + ks * 32 + g * 8);
  }

  facc accO[2][4];
  const facc fz = {0.f, 0.f, 0.f, 0.f};
#pragma unroll
  for (int mt = 0; mt < 2; mt++)
#pragma unroll
    for (int dt = 0; dt < 4; dt++) accO[mt][dt] = fz;
  float lrow[2][4];
#pragma unroll
  for (int mt = 0; mt < 2; mt++)
#pragma unroll
    for (int r = 0; r < 4; r++) lrow[mt][r] = 0.f;

  const short* Kb = keysb + (size_t)b * KP * D_ + h * DH_;
  const short* Vb = vTb + ((size_t)b * H_ + h) * DH_ * KP;

  const int srow = t >> 3, sch = (t & 7) * 8;

#pragma unroll
  for (int i = 0; i < 2; i++) {
    const int row = srow + 32 * i;
    *(short8*)(&Kt[0][row * 72 + sch]) = *(const short8*)(Kb + (size_t)row * D_ + sch);
    *(short8*)(&Vt[0][row * 72 + sch]) = *(const short8*)(Vb + (size_t)row * KP + sch);
  }
  __syncthreads();

  for (int c = 0; c < 4; c++) {        // kp chunks of 64
    const int bi = c & 1;

    // T14 issue-early: next chunk's K/V global->reg (latency hides under QK)
    short8 kr[2], vr[2];
    if (c < 3) {
#pragma unroll
      for (int i = 0; i < 2; i++) {
        const int row = srow + 32 * i;
        kr[i] = *(const short8*)(Kb + (size_t)((c + 1) * 64 + row) * D_ + sch);
        vr[i] = *(const short8*)(Vb + (size_t)row * KP + (c + 1) * 64 + sch);
      }
    }

    // QK^T
    facc S[2][4];
#pragma unroll
    for (int mt = 0; mt < 2; mt++)
#pragma unroll
      for (int nt = 0; nt < 4; nt++) S[mt][nt] = fz;
#pragma unroll
    for (int ks = 0; ks < 2; ks++) {
      short8 bk[4];
#pragma unroll
      for (int nt = 0; nt < 4; nt++)
        bk[nt] = *(const short8*)(&Kt[bi][(16 * nt + lm) * 72 + ks * 32 + g * 8]);
#pragma unroll
      for (int mt = 0; mt < 2; mt++)
#pragma unroll
        for (int nt = 0; nt < 4; nt++)
          S[mt][nt] = __builtin_amdgcn_mfma_f32_16x16x32_bf16(aq[mt][ks], bk[nt], S[mt][nt], 0, 0, 0);
    }

    // T14 write-late: commit staged regs to the other buffer
    if (c < 3) {
#pragma unroll
      for (int i = 0; i < 2; i++) {
        const int row = srow + 32 * i;
        *(short8*)(&Kt[bi ^ 1][row * 72 + sch]) = kr[i];
        *(short8*)(&Vt[bi ^ 1][row * 72 + sch]) = vr[i];
      }
    }

    // exp (no max) + P -> LDS (bf16)
#pragma unroll
    for (int mt = 0; mt < 2; mt++)
#pragma unroll
      for (int r = 0; r < 4; r++) {
        float ps = 0.f;
        const int prow = (16 * mt + 4 * g + r) * PTS;
#pragma unroll
        for (int nt = 0; nt < 4; nt++) {
          const float p = __expf(S[mt][nt][r] * SCALE_);
          ps += p;
          Pt[w][prow + 16 * nt + lm] = f2b(p);
        }
        lrow[mt][r] += ps;
      }

    // PV
#pragma unroll
    for (int ks = 0; ks < 2; ks++) {
      short8 ap[2], bv[4];
#pragma unroll
      for (int mt = 0; mt < 2; mt++)
        ap[mt] = *(const short8*)(&Pt[w][(16 * mt + lm) * PTS + ks * 32 + g * 8]);
#pragma unroll
      for (int dt = 0; dt < 4; dt++)
        bv[dt] = *(const short8*)(&Vt[bi][(16 * dt + lm) * 72 + ks * 32 + g * 8]);
#pragma unroll
      for (int mt = 0; mt < 2; mt++)
#pragma unroll
        for (int dt = 0; dt < 4; dt++)
          accO[mt][dt] = __builtin_amdgcn_mfma_f32_16x16x32_bf16(ap[mt], bv[dt], accO[mt][dt], 0, 0, 0);
    }
    __syncthreads();
  }

#pragma unroll
  for (int mt = 0; mt < 2; mt++)
#pragma unroll
    for (int r = 0; r < 4; r++) {
      float ls = lrow[mt][r];
      ls += __shfl_xor(ls, 1);
      ls += __shfl_xor(ls, 2);
      ls += __shfl_xor(ls, 4);
      ls += __shfl_xor(ls, 8);
      const float inv = 1.0f / ls;
      const int l = l0w + 16 * mt + 4 * g + r;
#pragma unroll
      for (int dt = 0; dt < 4; dt++)
        out2b[((size_t)b * L_ + l) * D_ + h * DH_ + 16 * dt + lm] = f2b(accO[mt][dt][r] * inv);
    }
}

extern "C" void kernel_launch(void* const* d_in, const int* in_sizes, int n_in,
                              void* d_out, int out_size, void* d_ws, size_t ws_size,
                              hipStream_t stream)
{
  const float* x      = (const float*)d_in[0];
  const float* Wq     = (const float*)d_in[1];
  const float* Wk     = (const float*)d_in[2];
  const float* Wv     = (const float*)d_in[3];
  const float* proj_k = (const float*)d_in[4];
  const float* proj_v = (const float*)d_in[5];
  const float* Wo     = (const float*)d_in[6];
  const float* bo     = (const float*)d_in[7];
  float* out = (float*)d_out;

  short* ws     = (short*)d_ws;
  short* xqb    = ws;                    // 8388608
  short* xTb    = xqb    + 8388608;      // 8388608  [B][D][L]
  short* xb     = xTb    + 8388608;      // 8388608
  short* out2b  = xb;                    //          alias (xb dead after gemm1)
  short* Wqb    = xb     + 8388608;      // 1048576 (Wq,Wk,Wv,Wo contiguous)
  short* Wkb    = Wqb    + 1048576;
  short* Wvb    = Wkb    + 1048576;
  short* Wob    = Wvb    + 1048576;
  short* projTk = Wob    + 1048576;      // 524288 (projTk,projTv contiguous)
  short* projTv = projTk + 524288;
  short* xk2b   = projTv + 524288;       // 1048576 (adjacent xv2b)
  short* xv2b   = xk2b   + 1048576;
  short* keysb  = xv2b   + 1048576;
  short* valsb  = keysb  + 1048576;
  short* vT     = valsb  + 1048576;      // 1048576 [B][H][64][256]
  (void)Wkb; (void)Wvb; (void)projTv; (void)xv2b; (void)valsb;

  static bool attr_set = false;
  if (!attr_set) {
    (void)hipFuncSetAttribute(reinterpret_cast<const void*>(gemm8p),
                              hipFuncAttributeMaxDynamicSharedMemorySize, 147456);
    attr_set = true;
  }

  prepX<<<dim3(32, 64, 8), 256, 0, stream>>>(
      x, proj_k, proj_v, Wq, Wk, Wv, Wo, xb, xTb, projTk, Wqb);

  // 1. xqb = xb @ Wq^T   (grid (8 xcd-bands, 32), 512 thr, 144KB dyn LDS)
  gemm8p<<<dim3(8, 32, 1), 512, 147456, stream>>>(
      xb, Wqb, nullptr, nullptr, xqb, 8192, 1024, 1024);

  // 2. xk2b/xv2b = projT @ xT[b]^T  (z = sel*4 + b), pipelined 64^2
  gemm_p64<<<dim3(16, 4, 8), 256, 0, stream>>>(
      projTk, xTb, nullptr, nullptr, xk2b, nullptr, 256, 1024, 2048,
      524288, 0, 0, (long)D_ * L_, 1048576, 262144, 4);

  // 3. keysb = xk2b @ Wk^T (z=0); vT = transpose(xv2b @ Wv^T) (z=1)
  gemm_p64<<<dim3(16, 16, 2), 256, 0, stream>>>(
      xk2b, Wkb, nullptr, nullptr, keysb, vT, 1024, 1024, 1024,
      1048576, 0, 1048576, 0, 0, 0, 1);

  // 4. attention (LDS-staged, T14, double-buffered)
  attn_mfma<<<dim3(16, 16, 4), 256, 0, stream>>>(xqb, keysb, vT, out2b);

  // 5. out = out2b @ Wo^T + bo (fp32 out)
  gemm8p<<<dim3(8, 32, 1), 512, 147456, stream>>>(
      out2b, Wob, bo, out, nullptr, 8192, 1024, 1024);
}